// Round 1
// baseline (1873.434 us; speedup 1.0000x reference)
//
#include <hip/hip_runtime.h>
#include <hip/hip_bf16.h>
#include <math.h>

#define NB   2
#define CIN  64
#define CENC 96
#define DK   64
#define DV   64
#define HH   96
#define WW   96
#define LL   (HH*WW)          // 9216
#define LOG2E 1.44269504088896340736f

#define QT 256                // queries per block (1 per thread)
#define JT 64                 // keys per LDS tile

// ---------------- projection: Q,K (L2-normalized per position) ----------------
__global__ __launch_bounds__(256) void proj_qk_kernel(
    const float* __restrict__ x_enc,
    const float* __restrict__ Wq, const float* __restrict__ bq,
    const float* __restrict__ Wk, const float* __restrict__ bk,
    float* __restrict__ Qn, float* __restrict__ Kn)
{
    int g = blockIdx.x * 256 + threadIdx.x;       // 0 .. NB*LL-1
    int b = g / LL, l = g - b * LL;

    float xe[CENC];
    const float* xb = x_enc + (size_t)b * CENC * LL + l;
#pragma unroll
    for (int c = 0; c < CENC; ++c) xe[c] = xb[(size_t)c * LL];

    float q[DK];
    // ---- Q ----
    float ss = 0.f;
#pragma unroll 2
    for (int k = 0; k < DK; ++k) {
        float acc = bq[k];
        const float* wr = Wq + k * CENC;
#pragma unroll
        for (int c = 0; c < CENC; ++c) acc = fmaf(wr[c], xe[c], acc);
        q[k] = acc; ss += acc * acc;
    }
    float sc = 1.f / fmaxf(sqrtf(ss), 1e-6f);
    float* qo = Qn + (size_t)g * DK;
#pragma unroll
    for (int k = 0; k < DK; ++k) qo[k] = q[k] * sc;

    // ---- K ----
    ss = 0.f;
#pragma unroll 2
    for (int k = 0; k < DK; ++k) {
        float acc = bk[k];
        const float* wr = Wk + k * CENC;
#pragma unroll
        for (int c = 0; c < CENC; ++c) acc = fmaf(wr[c], xe[c], acc);
        q[k] = acc; ss += acc * acc;
    }
    sc = 1.f / fmaxf(sqrtf(ss), 1e-6f);
    float* ko = Kn + (size_t)g * DK;
#pragma unroll
    for (int k = 0; k < DK; ++k) ko[k] = q[k] * sc;
}

// ---------------- projection: V ----------------
__global__ __launch_bounds__(256) void proj_v_kernel(
    const float* __restrict__ x,
    const float* __restrict__ Wv, const float* __restrict__ bv,
    float* __restrict__ V)
{
    int g = blockIdx.x * 256 + threadIdx.x;
    int b = g / LL, l = g - b * LL;

    float xv[CIN];
    const float* xb = x + (size_t)b * CIN * LL + l;
#pragma unroll
    for (int c = 0; c < CIN; ++c) xv[c] = xb[(size_t)c * LL];

    float* vo = V + (size_t)g * DV;
#pragma unroll 2
    for (int k = 0; k < DV; ++k) {
        float acc = bv[k];
        const float* wr = Wv + k * CIN;
#pragma unroll
        for (int c = 0; c < CIN; ++c) acc = fmaf(wr[c], xv[c], acc);
        vo[k] = acc;
    }
}

// ---------------- flash attention (fixed softmax shift: logits <= 1) ----------------
__global__ __launch_bounds__(256) void flash_kernel(
    const float* __restrict__ Qn, const float* __restrict__ Kn,
    const float* __restrict__ V,
    float* __restrict__ Sp, float* __restrict__ Rp,
    int JS, int jchunk)
{
    __shared__ float Kl[JT][DK];
    __shared__ float Vl[JT][DV];

    int bid = blockIdx.x;
    int js  = bid % JS;
    int qt  = (bid / JS) % (LL / QT);
    int b   = bid / (JS * (LL / QT));
    int tid = threadIdx.x;
    int i   = qt * QT + tid;

    float4 q4[16];
    const float4* qsrc = (const float4*)(Qn + ((size_t)b * LL + i) * DK);
#pragma unroll
    for (int t = 0; t < 16; ++t) q4[t] = qsrc[t];

    float4 r4[16];
#pragma unroll
    for (int t = 0; t < 16; ++t) r4[t] = make_float4(0.f, 0.f, 0.f, 0.f);
    float s = 0.f;

    int j0 = js * jchunk;
    for (int jt = 0; jt < jchunk; jt += JT) {
        const float4* ks = (const float4*)(Kn + ((size_t)b * LL + j0 + jt) * DK);
        const float4* vs = (const float4*)(V  + ((size_t)b * LL + j0 + jt) * DV);
        __syncthreads();
        float4* kl = (float4*)&Kl[0][0];
        float4* vl = (float4*)&Vl[0][0];
#pragma unroll
        for (int r = 0; r < 4; ++r) {
            kl[tid + 256 * r] = ks[tid + 256 * r];
            vl[tid + 256 * r] = vs[tid + 256 * r];
        }
        __syncthreads();

#pragma unroll 2
        for (int jj = 0; jj < JT; ++jj) {
            const float4* kr = (const float4*)&Kl[jj][0];
            float ax = 0.f, ay = 0.f, az = 0.f, aw = 0.f;
#pragma unroll
            for (int t = 0; t < 16; ++t) {
                float4 kv = kr[t];
                ax = fmaf(q4[t].x, kv.x, ax);
                ay = fmaf(q4[t].y, kv.y, ay);
                az = fmaf(q4[t].z, kv.z, az);
                aw = fmaf(q4[t].w, kv.w, aw);
            }
            float dot = (ax + ay) + (az + aw);
            float p = __builtin_amdgcn_exp2f(fmaf(dot, LOG2E, -LOG2E));
            s += p;
            const float4* vr = (const float4*)&Vl[jj][0];
#pragma unroll
            for (int t = 0; t < 16; ++t) {
                float4 vv = vr[t];
                r4[t].x = fmaf(p, vv.x, r4[t].x);
                r4[t].y = fmaf(p, vv.y, r4[t].y);
                r4[t].z = fmaf(p, vv.z, r4[t].z);
                r4[t].w = fmaf(p, vv.w, r4[t].w);
            }
        }
    }

    size_t base = ((size_t)b * JS + js) * LL + i;
    Sp[base] = s;
    float4* ro = (float4*)(Rp + base * (size_t)DV);
#pragma unroll
    for (int t = 0; t < 16; ++t) ro[t] = r4[t];
}

// ---------------- combine partials, write (B, dv, H, W) ----------------
__global__ __launch_bounds__(256) void combine_kernel(
    const float* __restrict__ Sp, const float* __restrict__ Rp,
    float* __restrict__ out, int JS)
{
    int g = blockIdx.x * 256 + threadIdx.x;       // 0 .. NB*LL-1
    int b = g / LL, l = g - b * LL;

    float s = 0.f;
    for (int js = 0; js < JS; ++js) s += Sp[((size_t)b * JS + js) * LL + l];
    float inv = 1.f / s;

    float4 r[16];
#pragma unroll
    for (int t = 0; t < 16; ++t) r[t] = make_float4(0.f, 0.f, 0.f, 0.f);
    for (int js = 0; js < JS; ++js) {
        const float4* rp = (const float4*)(Rp + (((size_t)b * JS + js) * LL + l) * (size_t)DV);
#pragma unroll
        for (int t = 0; t < 16; ++t) {
            float4 v = rp[t];
            r[t].x += v.x; r[t].y += v.y; r[t].z += v.z; r[t].w += v.w;
        }
    }
#pragma unroll
    for (int t = 0; t < 16; ++t) {
        out[((size_t)b * DV + (t*4+0)) * LL + l] = r[t].x * inv;
        out[((size_t)b * DV + (t*4+1)) * LL + l] = r[t].y * inv;
        out[((size_t)b * DV + (t*4+2)) * LL + l] = r[t].z * inv;
        out[((size_t)b * DV + (t*4+3)) * LL + l] = r[t].w * inv;
    }
}

extern "C" void kernel_launch(void* const* d_in, const int* in_sizes, int n_in,
                              void* d_out, int out_size, void* d_ws, size_t ws_size,
                              hipStream_t stream) {
    (void)in_sizes; (void)n_in; (void)out_size;
    const float* x     = (const float*)d_in[0];
    const float* x_enc = (const float*)d_in[1];
    const float* Wq    = (const float*)d_in[2];
    const float* bq    = (const float*)d_in[3];
    const float* Wk    = (const float*)d_in[4];
    const float* bk    = (const float*)d_in[5];
    const float* Wv    = (const float*)d_in[6];
    const float* bv    = (const float*)d_in[7];
    float* out = (float*)d_out;
    float* ws  = (float*)d_ws;

    const size_t nQ = (size_t)NB * LL * DK;       // 1,179,648 floats
    float* Qn = ws;
    float* Kn = ws + nQ;
    float* Vv = ws + 2 * nQ;

    // pick largest j-split whose partial buffers fit in the workspace
    int JS = 16;
    while (JS > 1) {
        size_t need = (3 * nQ + (size_t)NB * JS * LL * (1 + DV)) * sizeof(float);
        if (need <= ws_size) break;
        JS >>= 1;
    }
    float* Sp = ws + 3 * nQ;
    float* Rp = Sp + (size_t)NB * JS * LL;
    int jchunk = LL / JS;

    proj_qk_kernel<<<(NB * LL) / 256, 256, 0, stream>>>(x_enc, Wq, bq, Wk, bk, Qn, Kn);
    proj_v_kernel <<<(NB * LL) / 256, 256, 0, stream>>>(x, Wv, bv, Vv);
    flash_kernel  <<<NB * (LL / QT) * JS, 256, 0, stream>>>(Qn, Kn, Vv, Sp, Rp, JS, jchunk);
    combine_kernel<<<(NB * LL) / 256, 256, 0, stream>>>(Sp, Rp, out, JS);
}

// Round 2
// 286.738 us; speedup vs baseline: 6.5336x; 6.5336x over previous
//
#include <hip/hip_runtime.h>
#include <hip/hip_bf16.h>
#include <math.h>

#define NB   2
#define CIN  64
#define CENC 96
#define DK   64
#define DV   64
#define LL   9216
#define QBLK 128
#define KVBLK 64
#define NQT  (LL/QBLK)          // 72
#define LOG2E 1.44269504088896340736f

typedef __attribute__((ext_vector_type(8))) short short8;
typedef __attribute__((ext_vector_type(4))) float f32x4;
typedef __attribute__((ext_vector_type(2))) unsigned int uint2v;
typedef unsigned int uint;

__device__ inline void gload16(const void* g, void* l) {
    __builtin_amdgcn_global_load_lds(
        (const __attribute__((address_space(1))) unsigned int*)g,
        (__attribute__((address_space(3))) unsigned int*)l, 16, 0, 0);
}

__device__ inline unsigned short f2bf(float f) {
    union { float f; uint u; } v; v.f = f;
    uint r = (v.u + 0x7FFFu + ((v.u >> 16) & 1u)) >> 16;
    return (unsigned short)r;
}

__device__ inline uint pack_bf16x2(float lo, float hi) {
    __hip_bfloat162 h = __float22bfloat162_rn(float2{lo, hi});
    union { __hip_bfloat162 h; uint u; } cvt; cvt.h = h;
    return cvt.u;
}

// ---------------- projection: Q,K -> bf16 rows (B,L,64), L2-normalized ----------------
__global__ __launch_bounds__(256) void proj_qk_kernel(
    const float* __restrict__ x_enc,
    const float* __restrict__ Wq, const float* __restrict__ bq,
    const float* __restrict__ Wk, const float* __restrict__ bk,
    unsigned short* __restrict__ Qb, unsigned short* __restrict__ Kb)
{
    int g = blockIdx.x * 256 + threadIdx.x;
    int b = g / LL, l = g - b * LL;

    float xe[CENC];
    const float* xb = x_enc + (size_t)b * CENC * LL + l;
#pragma unroll
    for (int c = 0; c < CENC; ++c) xe[c] = xb[(size_t)c * LL];

    float q[DK];
    float ss = 0.f;
#pragma unroll 2
    for (int k = 0; k < DK; ++k) {
        float acc = bq[k];
        const float* wr = Wq + k * CENC;
#pragma unroll
        for (int c = 0; c < CENC; ++c) acc = fmaf(wr[c], xe[c], acc);
        q[k] = acc; ss += acc * acc;
    }
    float sc = 1.f / fmaxf(sqrtf(ss), 1e-6f);
    {
        uint ow[32];
#pragma unroll
        for (int t = 0; t < 32; ++t)
            ow[t] = (uint)f2bf(q[2*t] * sc) | ((uint)f2bf(q[2*t+1] * sc) << 16);
        uint4* dst = (uint4*)(Qb + (size_t)g * DK);
#pragma unroll
        for (int t = 0; t < 8; ++t) dst[t] = ((uint4*)ow)[t];
    }

    ss = 0.f;
#pragma unroll 2
    for (int k = 0; k < DK; ++k) {
        float acc = bk[k];
        const float* wr = Wk + k * CENC;
#pragma unroll
        for (int c = 0; c < CENC; ++c) acc = fmaf(wr[c], xe[c], acc);
        q[k] = acc; ss += acc * acc;
    }
    sc = 1.f / fmaxf(sqrtf(ss), 1e-6f);
    {
        uint ow[32];
#pragma unroll
        for (int t = 0; t < 32; ++t)
            ow[t] = (uint)f2bf(q[2*t] * sc) | ((uint)f2bf(q[2*t+1] * sc) << 16);
        uint4* dst = (uint4*)(Kb + (size_t)g * DK);
#pragma unroll
        for (int t = 0; t < 8; ++t) dst[t] = ((uint4*)ow)[t];
    }
}

// ---------------- projection: V -> bf16 transposed (B,64,L) ----------------
__global__ __launch_bounds__(256) void proj_v_kernel(
    const float* __restrict__ x,
    const float* __restrict__ Wv, const float* __restrict__ bv,
    unsigned short* __restrict__ Vt)
{
    int g = blockIdx.x * 256 + threadIdx.x;
    int b = g / LL, l = g - b * LL;

    float xv[CIN];
    const float* xb = x + (size_t)b * CIN * LL + l;
#pragma unroll
    for (int c = 0; c < CIN; ++c) xv[c] = xb[(size_t)c * LL];

    unsigned short* vo = Vt + (size_t)b * 64 * LL + l;
#pragma unroll 2
    for (int k = 0; k < DV; ++k) {
        float acc = bv[k];
        const float* wr = Wv + k * CIN;
#pragma unroll
        for (int c = 0; c < CIN; ++c) acc = fmaf(wr[c], xv[c], acc);
        vo[(size_t)k * LL] = f2bf(acc);
    }
}

// ---------------- MFMA flash attention ----------------
// S^T = mfma(A=K, B=Q): lane holds S^T[j=hi*4+reg][i=li] per 16x16 tile.
// P (bf16) round-trips per-wave LDS; PV: R = mfma(A=P, B=V from Vt).
__global__ __launch_bounds__(256, 2) void flash_kernel(
    const unsigned short* __restrict__ Qb,
    const unsigned short* __restrict__ Kb,
    const unsigned short* __restrict__ Vt,
    float* __restrict__ Sp, float* __restrict__ Rp,
    int JS, int nt)
{
    __shared__ unsigned short Kl[KVBLK * 64];        // swizzled rows: chunk ^= row&7
    __shared__ unsigned short Vl[64 * KVBLK];        // Vt tile, swizzled
    __shared__ unsigned short Pl[4 * 2 * 16 * 72];   // per-wave P: [it*16+i][j], stride 72

    const int bid = blockIdx.x;
    const int qt  = bid % NQT;
    const int js  = (bid / NQT) % JS;
    const int b   = bid / (NQT * JS);
    const int tid = threadIdx.x;
    const int w = tid >> 6, lane = tid & 63;
    const int li = lane & 15, hi = lane >> 4;
    const int i0 = qt * QBLK + w * 32;

    // Q fragments (B operand): lane holds Q[i0+it*16+li][hi*8 + kc*32 .. +7]
    short8 qf[2][2];
#pragma unroll
    for (int it = 0; it < 2; ++it)
#pragma unroll
        for (int kc = 0; kc < 2; ++kc)
            qf[it][kc] = *(const short8*)(Qb + ((size_t)(b * LL + i0 + it * 16 + li)) * 64 + hi * 8 + kc * 32);

    // swizzled LDS read offsets (bytes) for K/V fragment reads
    const int a0 = li * 128 + (( hi     ) ^ (li & 7)) * 16;
    const int a1 = li * 128 + ((hi + 4) ^ (li & 7)) * 16;

    // staging: wave w fills dest bytes [w*1024, w*1024+1024) and +4096; lane l -> dest o
    const int o0 = w * 1024 + lane * 16;
    const int o1 = o0 + 4096;
    const int r0 = o0 >> 7, r1 = o1 >> 7;
    const int c0 = ((o0 >> 4) & 7) ^ (r0 & 7);
    const int c1 = ((o1 >> 4) & 7) ^ (r1 & 7);

    const unsigned short* KbB = Kb + (size_t)b * LL * 64;
    const unsigned short* VtB = Vt + (size_t)b * 64 * LL;

    f32x4 racc[2][4];
#pragma unroll
    for (int it = 0; it < 2; ++it)
#pragma unroll
        for (int vt = 0; vt < 4; ++vt)
            racc[it][vt] = (f32x4){0.f, 0.f, 0.f, 0.f};
    float ssum[2] = {0.f, 0.f};

    unsigned short* Plw = Pl + w * (2 * 16 * 72);

    int j0 = js * (nt * KVBLK);
    for (int t = 0; t < nt; ++t, j0 += KVBLK) {
        if (t) __syncthreads();
        gload16(KbB + (size_t)(j0 + r0) * 64 + c0 * 8, (char*)Kl + w * 1024);
        gload16(KbB + (size_t)(j0 + r1) * 64 + c1 * 8, (char*)Kl + w * 1024 + 4096);
        gload16(VtB + (size_t)r0 * LL + j0 + c0 * 8, (char*)Vl + w * 1024);
        gload16(VtB + (size_t)r1 * LL + j0 + c1 * 8, (char*)Vl + w * 1024 + 4096);
        __syncthreads();

        // ---- S^T tiles + softmax + P write ----
#pragma unroll
        for (int jt = 0; jt < 4; ++jt) {
            const short8 k0 = *(const short8*)((char*)Kl + jt * 2048 + a0);
            const short8 k1 = *(const short8*)((char*)Kl + jt * 2048 + a1);
#pragma unroll
            for (int it = 0; it < 2; ++it) {
                f32x4 acc = (f32x4){0.f, 0.f, 0.f, 0.f};
                acc = __builtin_amdgcn_mfma_f32_16x16x32_bf16(k0, qf[it][0], acc, 0, 0, 0);
                acc = __builtin_amdgcn_mfma_f32_16x16x32_bf16(k1, qf[it][1], acc, 0, 0, 0);
                float p0 = __builtin_amdgcn_exp2f(fmaf(acc[0], LOG2E, -LOG2E));
                float p1 = __builtin_amdgcn_exp2f(fmaf(acc[1], LOG2E, -LOG2E));
                float p2 = __builtin_amdgcn_exp2f(fmaf(acc[2], LOG2E, -LOG2E));
                float p3 = __builtin_amdgcn_exp2f(fmaf(acc[3], LOG2E, -LOG2E));
                ssum[it] += (p0 + p1) + (p2 + p3);
                uint2v u;
                u.x = pack_bf16x2(p0, p1);
                u.y = pack_bf16x2(p2, p3);
                *(uint2v*)((char*)Plw + (it * 16 + li) * 144 + (jt * 16 + hi * 4) * 2) = u;
            }
        }
        __asm__ volatile("" ::: "memory");   // keep P writes ordered before P reads

        // ---- PV ----
#pragma unroll
        for (int jc = 0; jc < 2; ++jc) {
            const short8 pa0 = *(const short8*)((char*)Plw + (0 * 16 + li) * 144 + jc * 64 + hi * 16);
            const short8 pa1 = *(const short8*)((char*)Plw + (1 * 16 + li) * 144 + jc * 64 + hi * 16);
            const int av = jc ? a1 : a0;
#pragma unroll
            for (int vt = 0; vt < 4; ++vt) {
                const short8 vb = *(const short8*)((char*)Vl + vt * 2048 + av);
                racc[0][vt] = __builtin_amdgcn_mfma_f32_16x16x32_bf16(pa0, vb, racc[0][vt], 0, 0, 0);
                racc[1][vt] = __builtin_amdgcn_mfma_f32_16x16x32_bf16(pa1, vb, racc[1][vt], 0, 0, 0);
            }
        }
        __asm__ volatile("" ::: "memory");   // P reads done before next iter's writes
    }

    // ---- epilogue ----
#pragma unroll
    for (int it = 0; it < 2; ++it) {
        float s = ssum[it];
        s += __shfl_xor(s, 16, 64);
        s += __shfl_xor(s, 32, 64);
        if (hi == 0) Sp[(size_t)(b * JS + js) * LL + i0 + it * 16 + li] = s;
    }
    const size_t rBase = (size_t)(b * JS + js) * 64;
#pragma unroll
    for (int it = 0; it < 2; ++it)
#pragma unroll
        for (int vt = 0; vt < 4; ++vt) {
            float4 val = make_float4(racc[it][vt][0], racc[it][vt][1], racc[it][vt][2], racc[it][vt][3]);
            *(float4*)&Rp[(rBase + vt * 16 + li) * LL + i0 + it * 16 + hi * 4] = val;
        }
}

// ---------------- combine partials: out[b][v][l] ----------------
__global__ __launch_bounds__(256) void combine_kernel(
    const float* __restrict__ Sp, const float* __restrict__ Rp,
    float* __restrict__ out, int JS)
{
    size_t g = (size_t)blockIdx.x * 256 + threadIdx.x;   // over NB*64*LL
    int l = (int)(g % LL);
    int v = (int)((g / LL) % 64);
    int b = (int)(g / ((size_t)64 * LL));
    float s = 0.f, r = 0.f;
    for (int js = 0; js < JS; ++js) {
        s += Sp[(size_t)(b * JS + js) * LL + l];
        r += Rp[((size_t)(b * JS + js) * 64 + v) * LL + l];
    }
    out[g] = r / s;
}

extern "C" void kernel_launch(void* const* d_in, const int* in_sizes, int n_in,
                              void* d_out, int out_size, void* d_ws, size_t ws_size,
                              hipStream_t stream) {
    (void)in_sizes; (void)n_in; (void)out_size;
    const float* x     = (const float*)d_in[0];
    const float* x_enc = (const float*)d_in[1];
    const float* Wq    = (const float*)d_in[2];
    const float* bq    = (const float*)d_in[3];
    const float* Wk    = (const float*)d_in[4];
    const float* bk    = (const float*)d_in[5];
    const float* Wv    = (const float*)d_in[6];
    const float* bv    = (const float*)d_in[7];
    float* out = (float*)d_out;
    char* ws = (char*)d_ws;

    const size_t nBF = (size_t)NB * LL * 64 * 2;   // bytes per bf16 buffer
    unsigned short* Qb = (unsigned short*)ws;
    unsigned short* Kb = (unsigned short*)(ws + nBF);
    unsigned short* Vt = (unsigned short*)(ws + 2 * nBF);

    int JS = 8;
    while (JS > 1) {
        size_t need = 3 * nBF + (size_t)NB * JS * LL * 4 + (size_t)NB * JS * 64 * LL * 4;
        if (need <= ws_size) break;
        JS >>= 1;
    }
    float* Sp = (float*)(ws + 3 * nBF);
    float* Rp = Sp + (size_t)NB * JS * LL;
    int nt = (LL / JS) / KVBLK;

    proj_qk_kernel<<<NB * LL / 256, 256, 0, stream>>>(x_enc, Wq, bq, Wk, bk, Qb, Kb);
    proj_v_kernel <<<NB * LL / 256, 256, 0, stream>>>(x, Wv, bv, Vt);
    flash_kernel  <<<NB * JS * NQT, 256, 0, stream>>>(Qb, Kb, Vt, Sp, Rp, JS, nt);
    combine_kernel<<<(NB * 64 * LL) / 256, 256, 0, stream>>>(Sp, Rp, out, JS);
}

// Round 3
// 123.478 us; speedup vs baseline: 15.1723x; 2.3222x over previous
//
#include <hip/hip_runtime.h>
#include <hip/hip_bf16.h>
#include <math.h>

#define NB   2
#define CIN  64
#define CENC 96
#define DK   64
#define DV   64
#define LL   9216
#define QBLK 128
#define KVBLK 64
#define NQT  (LL/QBLK)          // 72
#define LOG2E 1.44269504088896340736f

typedef __attribute__((ext_vector_type(8))) short short8;
typedef __attribute__((ext_vector_type(4))) float f32x4;
typedef __attribute__((ext_vector_type(2))) unsigned int uint2v;
typedef unsigned int uint;

__device__ inline void gload16(const void* g, void* l) {
    __builtin_amdgcn_global_load_lds(
        (const __attribute__((address_space(1))) unsigned int*)g,
        (__attribute__((address_space(3))) unsigned int*)l, 16, 0, 0);
}

__device__ inline unsigned short f2bf(float f) {
    union { float f; uint u; } v; v.f = f;
    uint r = (v.u + 0x7FFFu + ((v.u >> 16) & 1u)) >> 16;
    return (unsigned short)r;
}

__device__ inline uint pack_bf16x2(float lo, float hi) {
    __hip_bfloat162 h = __float22bfloat162_rn(float2{lo, hi});
    union { __hip_bfloat162 h; uint u; } cvt; cvt.h = h;
    return cvt.u;
}

// ---------------- projection: Q,K (lane = k, 16 positions/wave) ----------------
// Wt staged in LDS transposed with XOR swizzle [c][k^(c&31)]; x_enc read as
// wave-uniform scalar loads; L2-norm via cross-lane butterfly.
__global__ __launch_bounds__(256) void proj_qk_kernel(
    const float* __restrict__ x_enc,
    const float* __restrict__ Wq, const float* __restrict__ bq,
    const float* __restrict__ Wk, const float* __restrict__ bk,
    unsigned short* __restrict__ Qb, unsigned short* __restrict__ Kb)
{
    __shared__ float Wt[2][CENC * 64];   // 48KB
    const int tid = threadIdx.x;
    for (int idx = tid; idx < DK * CENC; idx += 256) {
        int k = idx / CENC, c = idx - k * CENC;        // coalesced global read
        Wt[0][c * 64 + (k ^ (c & 31))] = Wq[idx];      // swizzled LDS write
        Wt[1][c * 64 + (k ^ (c & 31))] = Wk[idx];
    }
    __syncthreads();

    const int w    = __builtin_amdgcn_readfirstlane(tid >> 6);
    const int lane = tid & 63;
    const int gw   = blockIdx.x * 4 + w;      // 0..1151
    const int p0g  = gw * 16;
    const int b    = p0g / LL;
    const int p0   = p0g - b * LL;

    float qa[16], ka[16];
    const float bqv = bq[lane], bkv = bk[lane];
#pragma unroll
    for (int p = 0; p < 16; ++p) { qa[p] = bqv; ka[p] = bkv; }

    const float* xp = x_enc + (size_t)b * CENC * LL + p0;
#pragma unroll 4
    for (int c = 0; c < CENC; ++c) {
        const float wq = Wt[0][c * 64 + (lane ^ (c & 31))];
        const float wk = Wt[1][c * 64 + (lane ^ (c & 31))];
        const float* xc = xp + (size_t)c * LL;
#pragma unroll
        for (int p = 0; p < 16; ++p) {
            const float xv = xc[p];              // uniform -> s_load
            qa[p] = fmaf(wq, xv, qa[p]);
            ka[p] = fmaf(wk, xv, ka[p]);
        }
    }

    unsigned short* qrow = Qb + (size_t)(b * LL + p0) * 64 + lane;
    unsigned short* krow = Kb + (size_t)(b * LL + p0) * 64 + lane;
#pragma unroll
    for (int p = 0; p < 16; ++p) {
        float sq = qa[p] * qa[p];
        float sk = ka[p] * ka[p];
#pragma unroll
        for (int m = 1; m < 64; m <<= 1) {
            sq += __shfl_xor(sq, m, 64);
            sk += __shfl_xor(sk, m, 64);
        }
        qrow[(size_t)p * 64] = f2bf(qa[p] * (1.f / fmaxf(sqrtf(sq), 1e-6f)));
        krow[(size_t)p * 64] = f2bf(ka[p] * (1.f / fmaxf(sqrtf(sk), 1e-6f)));
    }
}

// ---------------- projection: V (lane = v), block LDS transpose -> Vt[v][l] ----------------
__global__ __launch_bounds__(256) void proj_v_kernel(
    const float* __restrict__ x,
    const float* __restrict__ Wv, const float* __restrict__ bv,
    unsigned short* __restrict__ Vt)
{
    __shared__ float Wt[CIN * 64];              // 16KB, [c][v^(c&31)]
    __shared__ unsigned short Vl[64 * 64];      // [p_in_block][v], 8KB
    const int tid = threadIdx.x;
    for (int idx = tid; idx < DV * CIN; idx += 256) {
        int v = idx / CIN, c = idx - v * CIN;
        Wt[c * 64 + (v ^ (c & 31))] = Wv[idx];
    }
    __syncthreads();

    const int w    = __builtin_amdgcn_readfirstlane(tid >> 6);
    const int lane = tid & 63;
    const int l0g  = blockIdx.x * 64;           // block covers 64 positions
    const int b    = l0g / LL;
    const int l0   = l0g - b * LL;
    const int p0   = w * 16;

    float va[16];
    const float bvv = bv[lane];
#pragma unroll
    for (int p = 0; p < 16; ++p) va[p] = bvv;

    const float* xp = x + (size_t)b * CIN * LL + l0 + p0;
#pragma unroll 4
    for (int c = 0; c < CIN; ++c) {
        const float wv = Wt[c * 64 + (lane ^ (c & 31))];
        const float* xc = xp + (size_t)c * LL;
#pragma unroll
        for (int p = 0; p < 16; ++p) va[p] = fmaf(wv, xc[p], va[p]);
    }
#pragma unroll
    for (int p = 0; p < 16; ++p) Vl[(p0 + p) * 64 + lane] = f2bf(va[p]);
    __syncthreads();

    // transpose write: thread -> row v = tid&63, col chunk w2 = tid>>6 (16 l's = 32B)
    const int v = tid & 63, w2 = tid >> 6;
    uint pk[8];
#pragma unroll
    for (int j = 0; j < 8; ++j)
        pk[j] = (uint)Vl[(w2 * 16 + 2 * j) * 64 + v] |
                ((uint)Vl[(w2 * 16 + 2 * j + 1) * 64 + v] << 16);
    uint4* dst = (uint4*)(Vt + (size_t)b * 64 * LL + (size_t)v * LL + l0 + w2 * 16);
    dst[0] = make_uint4(pk[0], pk[1], pk[2], pk[3]);
    dst[1] = make_uint4(pk[4], pk[5], pk[6], pk[7]);
}

// ---------------- MFMA flash attention ----------------
__global__ __launch_bounds__(256, 2) void flash_kernel(
    const unsigned short* __restrict__ Qb,
    const unsigned short* __restrict__ Kb,
    const unsigned short* __restrict__ Vt,
    float* __restrict__ Sp, float* __restrict__ Rp,
    int JS, int nt)
{
    __shared__ unsigned short Kl[KVBLK * 64];        // swizzled rows: chunk ^= row&7
    __shared__ unsigned short Vl[64 * KVBLK];        // Vt tile, swizzled
    __shared__ unsigned short Pl[4 * 2 * 16 * 72];   // per-wave P: [it*16+i][j], stride 72

    const int bid = blockIdx.x;
    const int qt  = bid % NQT;
    const int js  = (bid / NQT) % JS;
    const int b   = bid / (NQT * JS);
    const int tid = threadIdx.x;
    const int w = tid >> 6, lane = tid & 63;
    const int li = lane & 15, hi = lane >> 4;
    const int i0 = qt * QBLK + w * 32;

    short8 qf[2][2];
#pragma unroll
    for (int it = 0; it < 2; ++it)
#pragma unroll
        for (int kc = 0; kc < 2; ++kc)
            qf[it][kc] = *(const short8*)(Qb + ((size_t)(b * LL + i0 + it * 16 + li)) * 64 + hi * 8 + kc * 32);

    const int a0 = li * 128 + (( hi     ) ^ (li & 7)) * 16;
    const int a1 = li * 128 + ((hi + 4) ^ (li & 7)) * 16;

    const int o0 = w * 1024 + lane * 16;
    const int o1 = o0 + 4096;
    const int r0 = o0 >> 7, r1 = o1 >> 7;
    const int c0 = ((o0 >> 4) & 7) ^ (r0 & 7);
    const int c1 = ((o1 >> 4) & 7) ^ (r1 & 7);

    const unsigned short* KbB = Kb + (size_t)b * LL * 64;
    const unsigned short* VtB = Vt + (size_t)b * 64 * LL;

    f32x4 racc[2][4];
#pragma unroll
    for (int it = 0; it < 2; ++it)
#pragma unroll
        for (int vt = 0; vt < 4; ++vt)
            racc[it][vt] = (f32x4){0.f, 0.f, 0.f, 0.f};
    float ssum[2] = {0.f, 0.f};

    unsigned short* Plw = Pl + w * (2 * 16 * 72);

    int j0 = js * (nt * KVBLK);
    for (int t = 0; t < nt; ++t, j0 += KVBLK) {
        if (t) __syncthreads();
        gload16(KbB + (size_t)(j0 + r0) * 64 + c0 * 8, (char*)Kl + w * 1024);
        gload16(KbB + (size_t)(j0 + r1) * 64 + c1 * 8, (char*)Kl + w * 1024 + 4096);
        gload16(VtB + (size_t)r0 * LL + j0 + c0 * 8, (char*)Vl + w * 1024);
        gload16(VtB + (size_t)r1 * LL + j0 + c1 * 8, (char*)Vl + w * 1024 + 4096);
        __syncthreads();

#pragma unroll
        for (int jt = 0; jt < 4; ++jt) {
            const short8 k0 = *(const short8*)((char*)Kl + jt * 2048 + a0);
            const short8 k1 = *(const short8*)((char*)Kl + jt * 2048 + a1);
#pragma unroll
            for (int it = 0; it < 2; ++it) {
                f32x4 acc = (f32x4){0.f, 0.f, 0.f, 0.f};
                acc = __builtin_amdgcn_mfma_f32_16x16x32_bf16(k0, qf[it][0], acc, 0, 0, 0);
                acc = __builtin_amdgcn_mfma_f32_16x16x32_bf16(k1, qf[it][1], acc, 0, 0, 0);
                float p0 = __builtin_amdgcn_exp2f(fmaf(acc[0], LOG2E, -LOG2E));
                float p1 = __builtin_amdgcn_exp2f(fmaf(acc[1], LOG2E, -LOG2E));
                float p2 = __builtin_amdgcn_exp2f(fmaf(acc[2], LOG2E, -LOG2E));
                float p3 = __builtin_amdgcn_exp2f(fmaf(acc[3], LOG2E, -LOG2E));
                ssum[it] += (p0 + p1) + (p2 + p3);
                uint2v u;
                u.x = pack_bf16x2(p0, p1);
                u.y = pack_bf16x2(p2, p3);
                *(uint2v*)((char*)Plw + (it * 16 + li) * 144 + (jt * 16 + hi * 4) * 2) = u;
            }
        }
        __asm__ volatile("" ::: "memory");

#pragma unroll
        for (int jc = 0; jc < 2; ++jc) {
            const short8 pa0 = *(const short8*)((char*)Plw + (0 * 16 + li) * 144 + jc * 64 + hi * 16);
            const short8 pa1 = *(const short8*)((char*)Plw + (1 * 16 + li) * 144 + jc * 64 + hi * 16);
            const int av = jc ? a1 : a0;
#pragma unroll
            for (int vt = 0; vt < 4; ++vt) {
                const short8 vb = *(const short8*)((char*)Vl + vt * 2048 + av);
                racc[0][vt] = __builtin_amdgcn_mfma_f32_16x16x32_bf16(pa0, vb, racc[0][vt], 0, 0, 0);
                racc[1][vt] = __builtin_amdgcn_mfma_f32_16x16x32_bf16(pa1, vb, racc[1][vt], 0, 0, 0);
            }
        }
        __asm__ volatile("" ::: "memory");
    }

#pragma unroll
    for (int it = 0; it < 2; ++it) {
        float s = ssum[it];
        s += __shfl_xor(s, 16, 64);
        s += __shfl_xor(s, 32, 64);
        if (hi == 0) Sp[(size_t)(b * JS + js) * LL + i0 + it * 16 + li] = s;
    }
    const size_t rBase = (size_t)(b * JS + js) * 64;
#pragma unroll
    for (int it = 0; it < 2; ++it)
#pragma unroll
        for (int vt = 0; vt < 4; ++vt) {
            float4 val = make_float4(racc[it][vt][0], racc[it][vt][1], racc[it][vt][2], racc[it][vt][3]);
            *(float4*)&Rp[(rBase + vt * 16 + li) * LL + i0 + it * 16 + hi * 4] = val;
        }
}

// ---------------- combine partials: out[b][v][l] ----------------
__global__ __launch_bounds__(256) void combine_kernel(
    const float* __restrict__ Sp, const float* __restrict__ Rp,
    float* __restrict__ out, int JS)
{
    size_t g = (size_t)blockIdx.x * 256 + threadIdx.x;
    int l = (int)(g % LL);
    int v = (int)((g / LL) % 64);
    int b = (int)(g / ((size_t)64 * LL));
    float s = 0.f, r = 0.f;
    for (int js = 0; js < JS; ++js) {
        s += Sp[(size_t)(b * JS + js) * LL + l];
        r += Rp[((size_t)(b * JS + js) * 64 + v) * LL + l];
    }
    out[g] = r / s;
}

extern "C" void kernel_launch(void* const* d_in, const int* in_sizes, int n_in,
                              void* d_out, int out_size, void* d_ws, size_t ws_size,
                              hipStream_t stream) {
    (void)in_sizes; (void)n_in; (void)out_size;
    const float* x     = (const float*)d_in[0];
    const float* x_enc = (const float*)d_in[1];
    const float* Wq    = (const float*)d_in[2];
    const float* bq    = (const float*)d_in[3];
    const float* Wk    = (const float*)d_in[4];
    const float* bk    = (const float*)d_in[5];
    const float* Wv    = (const float*)d_in[6];
    const float* bv    = (const float*)d_in[7];
    float* out = (float*)d_out;
    char* ws = (char*)d_ws;

    const size_t nBF = (size_t)NB * LL * 64 * 2;
    unsigned short* Qb = (unsigned short*)ws;
    unsigned short* Kb = (unsigned short*)(ws + nBF);
    unsigned short* Vt = (unsigned short*)(ws + 2 * nBF);

    int JS = 8;
    while (JS > 1) {
        size_t need = 3 * nBF + (size_t)NB * JS * LL * 4 + (size_t)NB * JS * 64 * LL * 4;
        if (need <= ws_size) break;
        JS >>= 1;
    }
    float* Sp = (float*)(ws + 3 * nBF);
    float* Rp = Sp + (size_t)NB * JS * LL;
    int nt = (LL / JS) / KVBLK;

    proj_qk_kernel<<<NB * LL / 64, 256, 0, stream>>>(x_enc, Wq, bq, Wk, bk, Qb, Kb);
    proj_v_kernel <<<NB * LL / 64, 256, 0, stream>>>(x, Wv, bv, Vt);
    flash_kernel  <<<NB * JS * NQT, 256, 0, stream>>>(Qb, Kb, Vt, Sp, Rp, JS, nt);
    combine_kernel<<<(NB * 64 * LL) / 256, 256, 0, stream>>>(Sp, Rp, out, JS);
}

// Round 4
// 117.552 us; speedup vs baseline: 15.9371x; 1.0504x over previous
//
#include <hip/hip_runtime.h>
#include <hip/hip_bf16.h>
#include <math.h>

#define NB   2
#define CIN  64
#define CENC 96
#define DK   64
#define DV   64
#define LL   9216
#define QBLK 128
#define KVBLK 64
#define NQT  (LL/QBLK)          // 72
#define LOG2E 1.44269504088896340736f

typedef __attribute__((ext_vector_type(8))) short short8;
typedef __attribute__((ext_vector_type(4))) float f32x4;
typedef __attribute__((ext_vector_type(2))) unsigned int uint2v;
typedef unsigned int uint;

__device__ inline void gload16(const void* g, void* l) {
    __builtin_amdgcn_global_load_lds(
        (const __attribute__((address_space(1))) unsigned int*)g,
        (__attribute__((address_space(3))) unsigned int*)l, 16, 0, 0);
}

__device__ inline unsigned short f2bf(float f) {
    union { float f; uint u; } v; v.f = f;
    uint r = (v.u + 0x7FFFu + ((v.u >> 16) & 1u)) >> 16;
    return (unsigned short)r;
}

__device__ inline uint pack_bf16x2(float lo, float hi) {
    __hip_bfloat162 h = __float22bfloat162_rn(float2{lo, hi});
    union { __hip_bfloat162 h; uint u; } cvt; cvt.h = h;
    return cvt.u;
}

// ---------------- projection: Q,K (lane = k, 16 positions/wave) ----------------
__global__ __launch_bounds__(256) void proj_qk_kernel(
    const float* __restrict__ x_enc,
    const float* __restrict__ Wq, const float* __restrict__ bq,
    const float* __restrict__ Wk, const float* __restrict__ bk,
    unsigned short* __restrict__ Qb, unsigned short* __restrict__ Kb)
{
    __shared__ float Wt[2][CENC * 64];   // 48KB
    const int tid = threadIdx.x;
    for (int idx = tid; idx < DK * CENC; idx += 256) {
        int k = idx / CENC, c = idx - k * CENC;
        Wt[0][c * 64 + (k ^ (c & 31))] = Wq[idx];
        Wt[1][c * 64 + (k ^ (c & 31))] = Wk[idx];
    }
    __syncthreads();

    const int w    = __builtin_amdgcn_readfirstlane(tid >> 6);
    const int lane = tid & 63;
    const int gw   = blockIdx.x * 4 + w;
    const int p0g  = gw * 16;
    const int b    = p0g / LL;
    const int p0   = p0g - b * LL;

    float qa[16], ka[16];
    const float bqv = bq[lane], bkv = bk[lane];
#pragma unroll
    for (int p = 0; p < 16; ++p) { qa[p] = bqv; ka[p] = bkv; }

    const float* xp = x_enc + (size_t)b * CENC * LL + p0;
#pragma unroll 4
    for (int c = 0; c < CENC; ++c) {
        const float wq = Wt[0][c * 64 + (lane ^ (c & 31))];
        const float wk = Wt[1][c * 64 + (lane ^ (c & 31))];
        const float* xc = xp + (size_t)c * LL;
#pragma unroll
        for (int p = 0; p < 16; ++p) {
            const float xv = xc[p];
            qa[p] = fmaf(wq, xv, qa[p]);
            ka[p] = fmaf(wk, xv, ka[p]);
        }
    }

    unsigned short* qrow = Qb + (size_t)(b * LL + p0) * 64 + lane;
    unsigned short* krow = Kb + (size_t)(b * LL + p0) * 64 + lane;
#pragma unroll
    for (int p = 0; p < 16; ++p) {
        float sq = qa[p] * qa[p];
        float sk = ka[p] * ka[p];
#pragma unroll
        for (int m = 1; m < 64; m <<= 1) {
            sq += __shfl_xor(sq, m, 64);
            sk += __shfl_xor(sk, m, 64);
        }
        qrow[(size_t)p * 64] = f2bf(qa[p] * (1.f / fmaxf(sqrtf(sq), 1e-6f)));
        krow[(size_t)p * 64] = f2bf(ka[p] * (1.f / fmaxf(sqrtf(sk), 1e-6f)));
    }
}

// ---------------- projection: V (lane = v), block LDS transpose -> Vt[v][l] ----------------
__global__ __launch_bounds__(256) void proj_v_kernel(
    const float* __restrict__ x,
    const float* __restrict__ Wv, const float* __restrict__ bv,
    unsigned short* __restrict__ Vt)
{
    __shared__ float Wt[CIN * 64];
    __shared__ unsigned short Vl[64 * 64];
    const int tid = threadIdx.x;
    for (int idx = tid; idx < DV * CIN; idx += 256) {
        int v = idx / CIN, c = idx - v * CIN;
        Wt[c * 64 + (v ^ (c & 31))] = Wv[idx];
    }
    __syncthreads();

    const int w    = __builtin_amdgcn_readfirstlane(tid >> 6);
    const int lane = tid & 63;
    const int l0g  = blockIdx.x * 64;
    const int b    = l0g / LL;
    const int l0   = l0g - b * LL;
    const int p0   = w * 16;

    float va[16];
    const float bvv = bv[lane];
#pragma unroll
    for (int p = 0; p < 16; ++p) va[p] = bvv;

    const float* xp = x + (size_t)b * CIN * LL + l0 + p0;
#pragma unroll 4
    for (int c = 0; c < CIN; ++c) {
        const float wv = Wt[c * 64 + (lane ^ (c & 31))];
        const float* xc = xp + (size_t)c * LL;
#pragma unroll
        for (int p = 0; p < 16; ++p) va[p] = fmaf(wv, xc[p], va[p]);
    }
#pragma unroll
    for (int p = 0; p < 16; ++p) Vl[(p0 + p) * 64 + lane] = f2bf(va[p]);
    __syncthreads();

    const int v = tid & 63, w2 = tid >> 6;
    uint pk[8];
#pragma unroll
    for (int j = 0; j < 8; ++j)
        pk[j] = (uint)Vl[(w2 * 16 + 2 * j) * 64 + v] |
                ((uint)Vl[(w2 * 16 + 2 * j + 1) * 64 + v] << 16);
    uint4* dst = (uint4*)(Vt + (size_t)b * 64 * LL + (size_t)v * LL + l0 + w2 * 16);
    dst[0] = make_uint4(pk[0], pk[1], pk[2], pk[3]);
    dst[1] = make_uint4(pk[4], pk[5], pk[6], pk[7]);
}

// ---------------- MFMA flash attention, 2-phase double-buffered ----------------
__global__ __launch_bounds__(256, 3) void flash_kernel(
    const unsigned short* __restrict__ Qb,
    const unsigned short* __restrict__ Kb,
    const unsigned short* __restrict__ Vt,
    float* __restrict__ Sp, float* __restrict__ Rp,
    int JS, int nt)
{
    __shared__ unsigned short Kl[2][KVBLK * 64];     // 2 x 8KB, XOR-swizzled rows
    __shared__ unsigned short Vl[2][64 * KVBLK];     // 2 x 8KB
    __shared__ unsigned short Pl[4 * 32 * 64];       // per-wave P: 32 rows x 128B, XOR-swizzled

    // XCD-aware bijective swizzle (grid divisible by 8)
    const int bid0  = blockIdx.x;
    const int chunk = gridDim.x >> 3;
    const int bid   = (bid0 & 7) * chunk + (bid0 >> 3);

    const int qt  = bid % NQT;
    const int js  = (bid / NQT) % JS;
    const int b   = bid / (NQT * JS);
    const int tid = threadIdx.x;
    const int w = tid >> 6, lane = tid & 63;
    const int li = lane & 15, hi = lane >> 4;
    const int i0 = qt * QBLK + w * 32;

    short8 qf[2][2];
#pragma unroll
    for (int it = 0; it < 2; ++it)
#pragma unroll
        for (int kc = 0; kc < 2; ++kc)
            qf[it][kc] = *(const short8*)(Qb + ((size_t)(b * LL + i0 + it * 16 + li)) * 64 + hi * 8 + kc * 32);

    // swizzled LDS read offsets (bytes) for K/V fragment reads
    const int a0 = li * 128 + (( hi     ) ^ (li & 7)) * 16;
    const int a1 = li * 128 + ((hi + 4) ^ (li & 7)) * 16;

    // staging: wave w fills dest bytes [w*1024, +1024) and +4096; lane -> (row, swizzled chunk)
    const int o0 = w * 1024 + lane * 16;
    const int o1 = o0 + 4096;
    const int r0 = o0 >> 7, r1 = o1 >> 7;
    const int c0 = ((o0 >> 4) & 7) ^ (r0 & 7);
    const int c1 = ((o1 >> 4) & 7) ^ (r1 & 7);

    const unsigned short* KbB = Kb + (size_t)b * LL * 64;
    const unsigned short* VtB = Vt + (size_t)b * 64 * LL;

    f32x4 racc[2][4];
#pragma unroll
    for (int it = 0; it < 2; ++it)
#pragma unroll
        for (int vt = 0; vt < 4; ++vt)
            racc[it][vt] = (f32x4){0.f, 0.f, 0.f, 0.f};
    float ssum[2] = {0.f, 0.f};

    char* Plw = (char*)Pl + w * 4096;

    int j0 = js * (nt * KVBLK);
    // prologue: stage tile 0 into buffer 0
    gload16(KbB + (size_t)(j0 + r0) * 64 + c0 * 8, (char*)Kl[0] + w * 1024);
    gload16(KbB + (size_t)(j0 + r1) * 64 + c1 * 8, (char*)Kl[0] + w * 1024 + 4096);
    gload16(VtB + (size_t)r0 * LL + j0 + c0 * 8, (char*)Vl[0] + w * 1024);
    gload16(VtB + (size_t)r1 * LL + j0 + c1 * 8, (char*)Vl[0] + w * 1024 + 4096);

    for (int t = 0; t < nt; ++t, j0 += KVBLK) {
        // compiler emits s_waitcnt vmcnt(0) before s_barrier: drains exactly the
        // loads for the tile we are about to compute (prefetch not yet issued).
        __syncthreads();
        const int bb = t & 1;
        if (t + 1 < nt) {
            const int j1 = j0 + KVBLK;
            gload16(KbB + (size_t)(j1 + r0) * 64 + c0 * 8, (char*)Kl[bb ^ 1] + w * 1024);
            gload16(KbB + (size_t)(j1 + r1) * 64 + c1 * 8, (char*)Kl[bb ^ 1] + w * 1024 + 4096);
            gload16(VtB + (size_t)r0 * LL + j1 + c0 * 8, (char*)Vl[bb ^ 1] + w * 1024);
            gload16(VtB + (size_t)r1 * LL + j1 + c1 * 8, (char*)Vl[bb ^ 1] + w * 1024 + 4096);
        }
        const char* Klb = (const char*)Kl[bb];
        const char* Vlb = (const char*)Vl[bb];

        // ---- S^T tiles + softmax + P write (per-wave LDS, swizzled 128B rows) ----
#pragma unroll
        for (int jt = 0; jt < 4; ++jt) {
            const short8 k0 = *(const short8*)(Klb + jt * 2048 + a0);
            const short8 k1 = *(const short8*)(Klb + jt * 2048 + a1);
#pragma unroll
            for (int it = 0; it < 2; ++it) {
                f32x4 acc = (f32x4){0.f, 0.f, 0.f, 0.f};
                acc = __builtin_amdgcn_mfma_f32_16x16x32_bf16(k0, qf[it][0], acc, 0, 0, 0);
                acc = __builtin_amdgcn_mfma_f32_16x16x32_bf16(k1, qf[it][1], acc, 0, 0, 0);
                float p0 = __builtin_amdgcn_exp2f(fmaf(acc[0], LOG2E, -LOG2E));
                float p1 = __builtin_amdgcn_exp2f(fmaf(acc[1], LOG2E, -LOG2E));
                float p2 = __builtin_amdgcn_exp2f(fmaf(acc[2], LOG2E, -LOG2E));
                float p3 = __builtin_amdgcn_exp2f(fmaf(acc[3], LOG2E, -LOG2E));
                ssum[it] += (p0 + p1) + (p2 + p3);
                uint2v u;
                u.x = pack_bf16x2(p0, p1);
                u.y = pack_bf16x2(p2, p3);
                *(uint2v*)(Plw + (it * 16 + li) * 128
                               + (((jt * 2 + (hi >> 1)) ^ (li & 7)) * 16) + (hi & 1) * 8) = u;
            }
        }
        __asm__ volatile("" ::: "memory");

        // ---- PV ----
#pragma unroll
        for (int jc = 0; jc < 2; ++jc) {
            const short8 pa0 = *(const short8*)(Plw + (0 * 16 + li) * 128 + (((jc * 4 + hi) ^ (li & 7)) * 16));
            const short8 pa1 = *(const short8*)(Plw + (1 * 16 + li) * 128 + (((jc * 4 + hi) ^ (li & 7)) * 16));
            const int av = jc ? a1 : a0;
#pragma unroll
            for (int vt = 0; vt < 4; ++vt) {
                const short8 vb = *(const short8*)(Vlb + vt * 2048 + av);
                racc[0][vt] = __builtin_amdgcn_mfma_f32_16x16x32_bf16(pa0, vb, racc[0][vt], 0, 0, 0);
                racc[1][vt] = __builtin_amdgcn_mfma_f32_16x16x32_bf16(pa1, vb, racc[1][vt], 0, 0, 0);
            }
        }
        __asm__ volatile("" ::: "memory");
    }

    // ---- epilogue ----
#pragma unroll
    for (int it = 0; it < 2; ++it) {
        float s = ssum[it];
        s += __shfl_xor(s, 16, 64);
        s += __shfl_xor(s, 32, 64);
        if (hi == 0) Sp[(size_t)(b * JS + js) * LL + i0 + it * 16 + li] = s;
    }
    const size_t rBase = (size_t)(b * JS + js) * 64;
#pragma unroll
    for (int it = 0; it < 2; ++it)
#pragma unroll
        for (int vt = 0; vt < 4; ++vt) {
            float4 val = make_float4(racc[it][vt][0], racc[it][vt][1], racc[it][vt][2], racc[it][vt][3]);
            *(float4*)&Rp[(rBase + vt * 16 + li) * LL + i0 + it * 16 + hi * 4] = val;
        }
}

// ---------------- combine partials: out[b][v][l], float4 ----------------
__global__ __launch_bounds__(256) void combine_kernel(
    const float* __restrict__ Sp, const float* __restrict__ Rp,
    float* __restrict__ out, int JS)
{
    size_t g4 = ((size_t)blockIdx.x * 256 + threadIdx.x) * 4;
    int l = (int)(g4 % LL);
    int v = (int)((g4 / LL) % 64);
    int b = (int)(g4 / ((size_t)64 * LL));
    float4 s = make_float4(0.f, 0.f, 0.f, 0.f);
    float4 r = make_float4(0.f, 0.f, 0.f, 0.f);
    for (int js = 0; js < JS; ++js) {
        const float4 sv = *(const float4*)&Sp[(size_t)(b * JS + js) * LL + l];
        const float4 rv = *(const float4*)&Rp[((size_t)(b * JS + js) * 64 + v) * LL + l];
        s.x += sv.x; s.y += sv.y; s.z += sv.z; s.w += sv.w;
        r.x += rv.x; r.y += rv.y; r.z += rv.z; r.w += rv.w;
    }
    *(float4*)&out[g4] = make_float4(r.x / s.x, r.y / s.y, r.z / s.z, r.w / s.w);
}

extern "C" void kernel_launch(void* const* d_in, const int* in_sizes, int n_in,
                              void* d_out, int out_size, void* d_ws, size_t ws_size,
                              hipStream_t stream) {
    (void)in_sizes; (void)n_in; (void)out_size;
    const float* x     = (const float*)d_in[0];
    const float* x_enc = (const float*)d_in[1];
    const float* Wq    = (const float*)d_in[2];
    const float* bq    = (const float*)d_in[3];
    const float* Wk    = (const float*)d_in[4];
    const float* bk    = (const float*)d_in[5];
    const float* Wv    = (const float*)d_in[6];
    const float* bv    = (const float*)d_in[7];
    float* out = (float*)d_out;
    char* ws = (char*)d_ws;

    const size_t nBF = (size_t)NB * LL * 64 * 2;
    unsigned short* Qb = (unsigned short*)ws;
    unsigned short* Kb = (unsigned short*)(ws + nBF);
    unsigned short* Vt = (unsigned short*)(ws + 2 * nBF);

    int JS = 8;
    while (JS > 1) {
        size_t need = 3 * nBF + (size_t)NB * JS * LL * 4 + (size_t)NB * JS * 64 * LL * 4;
        if (need <= ws_size) break;
        JS >>= 1;
    }
    float* Sp = (float*)(ws + 3 * nBF);
    float* Rp = Sp + (size_t)NB * JS * LL;
    int nt = (LL / JS) / KVBLK;

    proj_qk_kernel<<<NB * LL / 64, 256, 0, stream>>>(x_enc, Wq, bq, Wk, bk, Qb, Kb);
    proj_v_kernel <<<NB * LL / 64, 256, 0, stream>>>(x, Wv, bv, Vt);
    flash_kernel  <<<NB * JS * NQT, 256, 0, stream>>>(Qb, Kb, Vt, Sp, Rp, JS, nt);
    combine_kernel<<<(NB * 64 * LL) / 1024, 256, 0, stream>>>(Sp, Rp, out, JS);
}

// Round 5
// 108.991 us; speedup vs baseline: 17.1889x; 1.0785x over previous
//
#include <hip/hip_runtime.h>
#include <hip/hip_bf16.h>
#include <math.h>

#define NB   2
#define CIN  64
#define CENC 96
#define DK   64
#define DV   64
#define LL   9216
#define QBLK 256
#define KVBLK 64
#define NQT  (LL/QBLK)          // 36
#define LOG2E 1.44269504088896340736f

typedef __attribute__((ext_vector_type(8)))  short short8;
typedef __attribute__((ext_vector_type(16))) float f32x16;
typedef __attribute__((ext_vector_type(2)))  unsigned int uint2v;
typedef unsigned int uint;

__device__ inline void gload16(const void* g, void* l) {
    __builtin_amdgcn_global_load_lds(
        (const __attribute__((address_space(1))) unsigned int*)g,
        (__attribute__((address_space(3))) unsigned int*)l, 16, 0, 0);
}

__device__ inline unsigned short f2bf(float f) {
    union { float f; uint u; } v; v.f = f;
    uint r = (v.u + 0x7FFFu + ((v.u >> 16) & 1u)) >> 16;
    return (unsigned short)r;
}

__device__ inline uint pack_bf16x2(float lo, float hi) {
    __hip_bfloat162 h = __float22bfloat162_rn(float2{lo, hi});
    union { __hip_bfloat162 h; uint u; } cvt; cvt.h = h;
    return cvt.u;
}

// exchange a[32:63] <-> b[0:31]
__device__ inline void plswap(uint& a, uint& b) {
#if __has_builtin(__builtin_amdgcn_permlane32_swap)
    uint2v r = __builtin_amdgcn_permlane32_swap(a, b, false, false);
    a = r.x; b = r.y;
#else
    const int lane = threadIdx.x & 63;
    uint t = (lane < 32) ? b : a;
    t = __shfl_xor(t, 32, 64);
    uint an = (lane < 32) ? a : t;
    uint bn = (lane < 32) ? t : b;
    a = an; b = bn;
#endif
}

// ---------------- fused projections ----------------
// blocks [0, nqk): Q,K projection + L2 norm (Q pre-scaled by LOG2E)
// blocks [nqk, 2*nqk): V projection + transpose to Vt[v][l]
__global__ __launch_bounds__(256) void proj_kernel(
    const float* __restrict__ x, const float* __restrict__ x_enc,
    const float* __restrict__ Wq, const float* __restrict__ bq,
    const float* __restrict__ Wk, const float* __restrict__ bk,
    const float* __restrict__ Wv, const float* __restrict__ bv,
    unsigned short* __restrict__ Qb, unsigned short* __restrict__ Kb,
    unsigned short* __restrict__ Vt, int nqk)
{
    __shared__ float sh[2 * CENC * 64];   // 48KB
    const int tid = threadIdx.x;

    if ((int)blockIdx.x < nqk) {
        float* Wt0 = sh;
        float* Wt1 = sh + CENC * 64;
        for (int idx = tid; idx < DK * CENC; idx += 256) {
            int k = idx / CENC, c = idx - k * CENC;
            Wt0[c * 64 + (k ^ (c & 31))] = Wq[idx];
            Wt1[c * 64 + (k ^ (c & 31))] = Wk[idx];
        }
        __syncthreads();

        const int w    = __builtin_amdgcn_readfirstlane(tid >> 6);
        const int lane = tid & 63;
        const int gw   = blockIdx.x * 4 + w;
        const int p0g  = gw * 16;
        const int b    = p0g / LL;
        const int p0   = p0g - b * LL;

        float qa[16], ka[16];
        const float bqv = bq[lane], bkv = bk[lane];
#pragma unroll
        for (int p = 0; p < 16; ++p) { qa[p] = bqv; ka[p] = bkv; }

        const float* xp = x_enc + (size_t)b * CENC * LL + p0;
#pragma unroll 4
        for (int c = 0; c < CENC; ++c) {
            const float wq = Wt0[c * 64 + (lane ^ (c & 31))];
            const float wk = Wt1[c * 64 + (lane ^ (c & 31))];
            const float* xc = xp + (size_t)c * LL;
#pragma unroll
            for (int p = 0; p < 16; ++p) {
                const float xv = xc[p];
                qa[p] = fmaf(wq, xv, qa[p]);
                ka[p] = fmaf(wk, xv, ka[p]);
            }
        }

        unsigned short* qrow = Qb + (size_t)(b * LL + p0) * 64 + lane;
        unsigned short* krow = Kb + (size_t)(b * LL + p0) * 64 + lane;
#pragma unroll
        for (int p = 0; p < 16; ++p) {
            float sq = qa[p] * qa[p];
            float sk = ka[p] * ka[p];
#pragma unroll
            for (int m = 1; m < 64; m <<= 1) {
                sq += __shfl_xor(sq, m, 64);
                sk += __shfl_xor(sk, m, 64);
            }
            qrow[(size_t)p * 64] = f2bf(qa[p] * (LOG2E / fmaxf(sqrtf(sq), 1e-6f)));
            krow[(size_t)p * 64] = f2bf(ka[p] * (1.f / fmaxf(sqrtf(sk), 1e-6f)));
        }
    } else {
        float* Wt = sh;                                        // 16KB
        unsigned short* Vsh = (unsigned short*)(sh + CIN * 64); // 8KB
        for (int idx = tid; idx < DV * CIN; idx += 256) {
            int v = idx / CIN, c = idx - v * CIN;
            Wt[c * 64 + (v ^ (c & 31))] = Wv[idx];
        }
        __syncthreads();

        const int w    = __builtin_amdgcn_readfirstlane(tid >> 6);
        const int lane = tid & 63;
        const int l0g  = ((int)blockIdx.x - nqk) * 64;
        const int b    = l0g / LL;
        const int l0   = l0g - b * LL;
        const int p0   = w * 16;

        float va[16];
        const float bvv = bv[lane];
#pragma unroll
        for (int p = 0; p < 16; ++p) va[p] = bvv;

        const float* xp = x + (size_t)b * CIN * LL + l0 + p0;
#pragma unroll 4
        for (int c = 0; c < CIN; ++c) {
            const float wv = Wt[c * 64 + (lane ^ (c & 31))];
            const float* xc = xp + (size_t)c * LL;
#pragma unroll
            for (int p = 0; p < 16; ++p) va[p] = fmaf(wv, xc[p], va[p]);
        }
#pragma unroll
        for (int p = 0; p < 16; ++p) Vsh[(p0 + p) * 64 + lane] = f2bf(va[p]);
        __syncthreads();

        const int v = tid & 63, w2 = tid >> 6;
        uint pk[8];
#pragma unroll
        for (int j = 0; j < 8; ++j)
            pk[j] = (uint)Vsh[(w2 * 16 + 2 * j) * 64 + v] |
                    ((uint)Vsh[(w2 * 16 + 2 * j + 1) * 64 + v] << 16);
        uint4* dst = (uint4*)(Vt + (size_t)b * 64 * LL + (size_t)v * LL + l0 + w2 * 16);
        dst[0] = make_uint4(pk[0], pk[1], pk[2], pk[3]);
        dst[1] = make_uint4(pk[4], pk[5], pk[6], pk[7]);
    }
}

// ---------------- MFMA flash attention: 32x32 tiles, in-register P ----------------
__global__ __launch_bounds__(256, 2) void flash_kernel(
    const unsigned short* __restrict__ Qb,
    const unsigned short* __restrict__ Kb,
    const unsigned short* __restrict__ Vt,
    float* __restrict__ Sp, float* __restrict__ Rp,
    int JS, int nt)
{
    __shared__ unsigned short Kl[2][KVBLK * 64];   // 2 x 8KB, XOR-swizzled rows
    __shared__ unsigned short Vl[2][64 * KVBLK];   // 2 x 8KB

    const int bid0  = blockIdx.x;
    const int chunk = gridDim.x >> 3;
    const int bid   = (bid0 & 7) * chunk + (bid0 >> 3);

    const int qt  = bid % NQT;
    const int js  = (bid / NQT) % JS;
    const int b   = bid / (NQT * JS);
    const int tid = threadIdx.x;
    const int w = tid >> 6, lane = tid & 63;
    const int ln = lane & 31, h = lane >> 5;
    const int i0w = qt * QBLK + w * 64;

    // Q B-fragments: lane holds Q[i = i0w+ig*32+ln][k = kc*16 + h*8 .. +7]
    short8 qf[2][4];
#pragma unroll
    for (int ig = 0; ig < 2; ++ig)
#pragma unroll
        for (int kc = 0; kc < 4; ++kc)
            qf[ig][kc] = *(const short8*)(Qb + ((size_t)(b * LL + i0w + ig * 32 + ln)) * 64 + kc * 16 + h * 8);

    // staging: wave w fills bytes [w*1024, +1024) and +4096 of each 8KB buffer
    const int o0 = w * 1024 + lane * 16;
    const int o1 = o0 + 4096;
    const int r0 = o0 >> 7, r1 = o1 >> 7;
    const int c0 = ((o0 >> 4) & 7) ^ (r0 & 7);
    const int c1 = ((o1 >> 4) & 7) ^ (r1 & 7);

    const unsigned short* KbB = Kb + (size_t)b * LL * 64;
    const unsigned short* VtB = Vt + (size_t)b * 64 * LL;

    f32x16 racc[2][2];
#pragma unroll
    for (int ig = 0; ig < 2; ++ig)
#pragma unroll
        for (int vg = 0; vg < 2; ++vg)
#pragma unroll
            for (int r = 0; r < 16; ++r) racc[ig][vg][r] = 0.f;
    float ssum[2] = {0.f, 0.f};

    int j0 = js * nt * KVBLK;
    // prologue: stage tile 0 into buffer 0
    gload16(KbB + (size_t)(j0 + r0) * 64 + c0 * 8, (char*)Kl[0] + w * 1024);
    gload16(KbB + (size_t)(j0 + r1) * 64 + c1 * 8, (char*)Kl[0] + w * 1024 + 4096);
    gload16(VtB + (size_t)r0 * LL + j0 + c0 * 8, (char*)Vl[0] + w * 1024);
    gload16(VtB + (size_t)r1 * LL + j0 + c1 * 8, (char*)Vl[0] + w * 1024 + 4096);

    for (int t = 0; t < nt; ++t, j0 += KVBLK) {
        __syncthreads();   // vmcnt(0) drain covers this tile's loads
        const int bb = t & 1;
        if (t + 1 < nt) {
            const int j1 = j0 + KVBLK;
            gload16(KbB + (size_t)(j1 + r0) * 64 + c0 * 8, (char*)Kl[bb ^ 1] + w * 1024);
            gload16(KbB + (size_t)(j1 + r1) * 64 + c1 * 8, (char*)Kl[bb ^ 1] + w * 1024 + 4096);
            gload16(VtB + (size_t)r0 * LL + j1 + c0 * 8, (char*)Vl[bb ^ 1] + w * 1024);
            gload16(VtB + (size_t)r1 * LL + j1 + c1 * 8, (char*)Vl[bb ^ 1] + w * 1024 + 4096);
        }
        const char* Klb = (const char*)Kl[bb];
        const char* Vlb = (const char*)Vl[bb];

#pragma unroll
        for (int jt = 0; jt < 2; ++jt) {
            // ---- S^T = mfma(A=K, B=Q): D[j][i], col i=ln, row j=(r&3)+8(r>>2)+4h ----
            f32x16 sacc[2];
#pragma unroll
            for (int ig = 0; ig < 2; ++ig)
#pragma unroll
                for (int r = 0; r < 16; ++r) sacc[ig][r] = 0.f;

            __builtin_amdgcn_s_setprio(1);
#pragma unroll
            for (int kc = 0; kc < 4; ++kc) {
                const int rowK = jt * 32 + ln;
                const short8 kf = *(const short8*)(Klb + rowK * 128 + (((kc << 1) + h) ^ (rowK & 7)) * 16);
                sacc[0] = __builtin_amdgcn_mfma_f32_32x32x16_bf16(kf, qf[0][kc], sacc[0], 0, 0, 0);
                sacc[1] = __builtin_amdgcn_mfma_f32_32x32x16_bf16(kf, qf[1][kc], sacc[1], 0, 0, 0);
            }
            __builtin_amdgcn_s_setprio(0);

            // ---- p = exp2(s'), pack to bf16, permlane -> PV A-fragments ----
            short8 pf[2][2];
#pragma unroll
            for (int ig = 0; ig < 2; ++ig) {
                float p[16];
#pragma unroll
                for (int r = 0; r < 16; ++r) p[r] = __builtin_amdgcn_exp2f(sacc[ig][r]);
                float s0 = 0.f;
#pragma unroll
                for (int r = 0; r < 16; r += 4) s0 += (p[r] + p[r + 1]) + (p[r + 2] + p[r + 3]);
                ssum[ig] += s0;
                uint u0[4], u1[4];
#pragma unroll
                for (int g = 0; g < 4; ++g) {
                    u0[g] = pack_bf16x2(p[4 * g], p[4 * g + 1]);
                    u1[g] = pack_bf16x2(p[4 * g + 2], p[4 * g + 3]);
                }
#pragma unroll
                for (int c = 0; c < 2; ++c) {
                    uint a0 = u0[2 * c], b0 = u0[2 * c + 1];
                    uint a1 = u1[2 * c], b1 = u1[2 * c + 1];
                    plswap(a0, b0);
                    plswap(a1, b1);
                    union { uint u[4]; short8 s; } P;
                    P.u[0] = a0; P.u[1] = a1; P.u[2] = b0; P.u[3] = b1;
                    pf[ig][c] = P.s;
                }
            }

            // ---- PV: racc[ig][vg] += mfma(A=P, B=V) ----
            __builtin_amdgcn_s_setprio(1);
#pragma unroll
            for (int c = 0; c < 2; ++c) {
                const int kcv = 2 * jt + c;
#pragma unroll
                for (int vg = 0; vg < 2; ++vg) {
                    const int rowV = vg * 32 + ln;
                    const short8 vf = *(const short8*)(Vlb + rowV * 128 + (((kcv << 1) + h) ^ (rowV & 7)) * 16);
                    racc[0][vg] = __builtin_amdgcn_mfma_f32_32x32x16_bf16(pf[0][c], vf, racc[0][vg], 0, 0, 0);
                    racc[1][vg] = __builtin_amdgcn_mfma_f32_32x32x16_bf16(pf[1][c], vf, racc[1][vg], 0, 0, 0);
                }
            }
            __builtin_amdgcn_s_setprio(0);
        }
    }

    // ---- epilogue ----
#pragma unroll
    for (int ig = 0; ig < 2; ++ig) {
        float s = ssum[ig] + __shfl_xor(ssum[ig], 32, 64);
        if (h == 0) Sp[(size_t)(b * JS + js) * LL + i0w + ig * 32 + ln] = s;
    }
    const size_t rBase = (size_t)(b * JS + js) * 64;
#pragma unroll
    for (int ig = 0; ig < 2; ++ig)
#pragma unroll
        for (int vg = 0; vg < 2; ++vg) {
            float* dst = Rp + (rBase + vg * 32 + ln) * (size_t)LL + i0w + ig * 32 + 4 * h;
#pragma unroll
            for (int rr = 0; rr < 4; ++rr) {
                float4 val = make_float4(racc[ig][vg][4 * rr + 0], racc[ig][vg][4 * rr + 1],
                                         racc[ig][vg][4 * rr + 2], racc[ig][vg][4 * rr + 3]);
                *(float4*)&dst[8 * rr] = val;
            }
        }
}

// ---------------- combine partials: out[b][v][l], float4 ----------------
__global__ __launch_bounds__(256) void combine_kernel(
    const float* __restrict__ Sp, const float* __restrict__ Rp,
    float* __restrict__ out, int JS)
{
    size_t g4 = ((size_t)blockIdx.x * 256 + threadIdx.x) * 4;
    int l = (int)(g4 % LL);
    int v = (int)((g4 / LL) % 64);
    int b = (int)(g4 / ((size_t)64 * LL));
    float4 s = make_float4(0.f, 0.f, 0.f, 0.f);
    float4 r = make_float4(0.f, 0.f, 0.f, 0.f);
    for (int js = 0; js < JS; ++js) {
        const float4 sv = *(const float4*)&Sp[(size_t)(b * JS + js) * LL + l];
        const float4 rv = *(const float4*)&Rp[((size_t)(b * JS + js) * 64 + v) * LL + l];
        s.x += sv.x; s.y += sv.y; s.z += sv.z; s.w += sv.w;
        r.x += rv.x; r.y += rv.y; r.z += rv.z; r.w += rv.w;
    }
    *(float4*)&out[g4] = make_float4(r.x / s.x, r.y / s.y, r.z / s.z, r.w / s.w);
}

extern "C" void kernel_launch(void* const* d_in, const int* in_sizes, int n_in,
                              void* d_out, int out_size, void* d_ws, size_t ws_size,
                              hipStream_t stream) {
    (void)in_sizes; (void)n_in; (void)out_size;
    const float* x     = (const float*)d_in[0];
    const float* x_enc = (const float*)d_in[1];
    const float* Wq    = (const float*)d_in[2];
    const float* bq    = (const float*)d_in[3];
    const float* Wk    = (const float*)d_in[4];
    const float* bk    = (const float*)d_in[5];
    const float* Wv    = (const float*)d_in[6];
    const float* bv    = (const float*)d_in[7];
    float* out = (float*)d_out;
    char* ws = (char*)d_ws;

    const size_t nBF = (size_t)NB * LL * 64 * 2;
    unsigned short* Qb = (unsigned short*)ws;
    unsigned short* Kb = (unsigned short*)(ws + nBF);
    unsigned short* Vt = (unsigned short*)(ws + 2 * nBF);

    // JS chain: integer nt and grid % 8 == 0
    int JS = 12;
    {
        const int cand[3] = {12, 8, 4};
        for (int ci = 0; ci < 3; ++ci) {
            JS = cand[ci];
            size_t need = 3 * nBF + (size_t)NB * JS * LL * 4 + (size_t)NB * JS * 64 * LL * 4;
            if (need <= ws_size) break;
        }
    }
    float* Sp = (float*)(ws + 3 * nBF);
    float* Rp = Sp + (size_t)NB * JS * LL;
    int nt = (LL / JS) / KVBLK;

    const int nqk = NB * LL / 64;   // 288
    proj_kernel  <<<2 * nqk, 256, 0, stream>>>(x, x_enc, Wq, bq, Wk, bk, Wv, bv, Qb, Kb, Vt, nqk);
    flash_kernel <<<NB * JS * NQT, 256, 0, stream>>>(Qb, Kb, Vt, Sp, Rp, JS, nt);
    combine_kernel<<<(NB * 64 * LL) / 1024, 256, 0, stream>>>(Sp, Rp, out, JS);
}